// Round 8
// baseline (4098.451 us; speedup 1.0000x reference)
//
#include <hip/hip_runtime.h>
#include <math.h>

// Problem constants
static constexpr int S_   = 512;     // hidden size
static constexpr int S4_  = 2048;    // 4*S (gates)
static constexpr int B_   = 16;      // batch
static constexpr int T_   = 256;     // tokens
static constexpr int G_   = 32;      // groups
static constexpr int GB_  = 512;     // G*B compose rows
static constexpr int V_   = 32000;   // vocab
static constexpr int NSTEPS_ = 321;  // 1 + G*(K+2)
static constexpr int NT_LSE_ = 250;  // vocab tiles of 128
static constexpr int SCAN_NB = 64;   // persistent scan blocks
static constexpr int MZX_ = 5184;    // padded zx rows (>= 321*16=5136)

typedef __attribute__((ext_vector_type(8))) short bf16x8;
typedef __attribute__((ext_vector_type(4))) float f32x4;

__device__ __forceinline__ float sigm(float x) { return 1.0f / (1.0f + expf(-x)); }

// bf16 round-to-nearest-even
__device__ __forceinline__ unsigned short f2bf(float x)
{
    unsigned int b = __float_as_uint(x);
    return (unsigned short)((b + 0x7FFFu + ((b >> 16) & 1u)) >> 16);
}
__device__ __forceinline__ float bf2f(unsigned short h)
{
    return __uint_as_float(((unsigned int)h) << 16);
}

// ---------------------------------------------------------------- gather e = emb[tokens] (fp32, tier-2)
__global__ __launch_bounds__(128)
void k_gather(const int* __restrict__ tokens, const float* __restrict__ emb,
              float* __restrict__ e)
{
    int row = blockIdx.x;
    int tok = tokens[row];
    const float4* src = (const float4*)(emb + (size_t)tok * S_);
    float4*       dst = (float4*)(e + (size_t)row * S_);
    dst[threadIdx.x] = src[threadIdx.x];
}

// ---------------------------------------------------------------- gather + split e -> bf16 hi/lo (v3)
__global__ __launch_bounds__(128)
void k_gather2(const int* __restrict__ tokens, const float* __restrict__ emb,
               unsigned short* __restrict__ ehi, unsigned short* __restrict__ elo)
{
    int row = blockIdx.x;
    int tok = tokens[row];
    const float4* src = (const float4*)(emb + (size_t)tok * S_);
    float4 v = src[threadIdx.x];
    size_t o = (size_t)row * S_ + threadIdx.x * 4;
    ushort4 hi, lo;
    hi.x = f2bf(v.x); lo.x = f2bf(v.x - bf2f(hi.x));
    hi.y = f2bf(v.y); lo.y = f2bf(v.y - bf2f(hi.y));
    hi.z = f2bf(v.z); lo.z = f2bf(v.z - bf2f(hi.z));
    hi.w = f2bf(v.w); lo.w = f2bf(v.w - bf2f(hi.w));
    *(ushort4*)(ehi + o) = hi;
    *(ushort4*)(elo + o) = lo;
}

// ---------------------------------------------------------------- open row split (emb[tokens[0]])
__global__ __launch_bounds__(128)
void k_osplit(const int* __restrict__ tokens, const float* __restrict__ emb,
              unsigned short* __restrict__ ophi, unsigned short* __restrict__ oplo)
{
    int tok = tokens[0];
    const float4* src = (const float4*)(emb + (size_t)tok * S_);
    float4 v = src[threadIdx.x];
    size_t o = threadIdx.x * 4;
    ushort4 hi, lo;
    hi.x = f2bf(v.x); lo.x = f2bf(v.x - bf2f(hi.x));
    hi.y = f2bf(v.y); lo.y = f2bf(v.y - bf2f(hi.y));
    hi.z = f2bf(v.z); lo.z = f2bf(v.z - bf2f(hi.z));
    hi.w = f2bf(v.w); lo.w = f2bf(v.w - bf2f(hi.w));
    *(ushort4*)(ophi + o) = hi;
    *(ushort4*)(oplo + o) = lo;
}

// ---------------------------------------------------------------- weight split: wcat[d][n][k<512:Wih | k>=512:Whh]
__global__ __launch_bounds__(256)
void k_wsplit_cat(const float* __restrict__ Wih_f, const float* __restrict__ Whh_f,
                  const float* __restrict__ Wih_b, const float* __restrict__ Whh_b,
                  unsigned short* __restrict__ wchi, unsigned short* __restrict__ wclo)
{
    size_t idx = ((size_t)blockIdx.x * 256 + threadIdx.x) * 8;  // 2*2048*1024 total
    int d = (int)(idx >> 21);
    size_t r = idx & ((1u << 21) - 1);
    int n = (int)(r >> 10);
    int k = (int)(r & 1023);
    const float* src = (k < 512) ? ((d ? Wih_b : Wih_f) + (size_t)n * 512 + k)
                                 : ((d ? Whh_b : Whh_f) + (size_t)n * 512 + (k - 512));
    float4 a = *(const float4*)src;
    float4 b = *(const float4*)(src + 4);
    float vv[8] = { a.x, a.y, a.z, a.w, b.x, b.y, b.z, b.w };
    unsigned short hi[8], lo[8];
#pragma unroll
    for (int i = 0; i < 8; ++i) { hi[i] = f2bf(vv[i]); lo[i] = f2bf(vv[i] - bf2f(hi[i])); }
    *(ushort4*)(wchi + idx)     = make_ushort4(hi[0], hi[1], hi[2], hi[3]);
    *(ushort4*)(wchi + idx + 4) = make_ushort4(hi[4], hi[5], hi[6], hi[7]);
    *(ushort4*)(wclo + idx)     = make_ushort4(lo[0], lo[1], lo[2], lo[3]);
    *(ushort4*)(wclo + idx + 4) = make_ushort4(lo[4], lo[5], lo[6], lo[7]);
}

// ---------------------------------------------------------------- weight split: Wih_s [2048][512]
__global__ __launch_bounds__(256)
void k_wsplit_s(const float* __restrict__ W, unsigned short* __restrict__ whi,
                unsigned short* __restrict__ wlo)
{
    size_t idx = ((size_t)blockIdx.x * 256 + threadIdx.x) * 8;  // 2048*512
    float4 a = *(const float4*)(W + idx);
    float4 b = *(const float4*)(W + idx + 4);
    float vv[8] = { a.x, a.y, a.z, a.w, b.x, b.y, b.z, b.w };
    unsigned short hi[8], lo[8];
#pragma unroll
    for (int i = 0; i < 8; ++i) { hi[i] = f2bf(vv[i]); lo[i] = f2bf(vv[i] - bf2f(hi[i])); }
    *(ushort4*)(whi + idx)     = make_ushort4(hi[0], hi[1], hi[2], hi[3]);
    *(ushort4*)(whi + idx + 4) = make_ushort4(hi[4], hi[5], hi[6], hi[7]);
    *(ushort4*)(wlo + idx)     = make_ushort4(lo[0], lo[1], lo[2], lo[3]);
    *(ushort4*)(wlo + idx + 4) = make_ushort4(lo[4], lo[5], lo[6], lo[7]);
}

// ---------------------------------------------------------------- fused MFMA compose step (bf16x3)
// grid: (u-tile 16, m-tile 4, d 2); block 256 (4 waves, wave tile 64x64).
// Tile: 128 m-rows x (32 units x 4 gates = 128 n). K=1024 = [x(512) | h(512)].
// 3 split products accumulate fp32: Ah*Bh + Ah*Bl + Al*Bh (~fp32 accuracy).
// Epilogue through LDS: gate update, writes h fp32 + h bf16-splits (ping-pong).
__global__ __launch_bounds__(256)
void k_compose2(const unsigned short* __restrict__ ehi, const unsigned short* __restrict__ elo,
                const unsigned short* __restrict__ wchi, const unsigned short* __restrict__ wclo,
                const unsigned short* __restrict__ hsp, unsigned short* __restrict__ hsp_out,
                const float* __restrict__ bih_f, const float* __restrict__ bhh_f,
                const float* __restrict__ bih_b, const float* __restrict__ bhh_b,
                float* __restrict__ hF, float* __restrict__ cF,
                float* __restrict__ hB, float* __restrict__ cB,
                int stepk)
{
    __shared__ float zt[128][132];
    __shared__ float bsum[128];
    const int t  = threadIdx.x;
    const int w  = t >> 6, l = t & 63;
    const int wm = w & 1, wn = w >> 1;
    const int lr = l & 15, lg = l >> 4;
    const int d  = blockIdx.z;
    const int u0 = blockIdx.x * 32;
    const int m0 = blockIdx.y * 128;
    const int child = d ? (7 - stepk) : stepk;
    const int pp = stepk & 1;

    const float* bih = d ? bih_b : bih_f;
    const float* bhh = d ? bhh_b : bhh_f;
    if (t < 128) {
        int g = t >> 5, ui = t & 31;
        bsum[t] = bih[g * 512 + u0 + ui] + bhh[g * 512 + u0 + ui];
    }

    const size_t HS = (size_t)512 * 512;
    const unsigned short* hsp_hi = hsp + ((size_t)(pp * 2 + d) * 2 + 0) * HS;
    const unsigned short* hsp_lo = hsp + ((size_t)(pp * 2 + d) * 2 + 1) * HS;

    const unsigned short *axh[4], *axl[4], *ahh[4], *ahl[4];
#pragma unroll
    for (int i = 0; i < 4; ++i) {
        int m = m0 + wm * 64 + i * 16 + lr;
        int g = m >> 4, b = m & 15;
        size_t xr = ((size_t)((g * 8 + child) * 16 + b)) * 512 + lg * 8;
        axh[i] = ehi + xr; axl[i] = elo + xr;
        size_t hr = (size_t)m * 512 + lg * 8;
        ahh[i] = hsp_hi + hr; ahl[i] = hsp_lo + hr;
    }
    const unsigned short *bh[4], *bl[4];
#pragma unroll
    for (int j = 0; j < 4; ++j) {
        int gate = 2 * wn + (j >> 1);
        int ui   = (j & 1) * 16 + lr;
        size_t br = ((size_t)(d * 2048 + gate * 512 + u0 + ui)) * 1024 + lg * 8;
        bh[j] = wchi + br; bl[j] = wclo + br;
    }

    f32x4 acc[4][4] = {};
    for (int sp = 0; sp < 3; ++sp) {
        const unsigned short* const* ax = (sp == 2) ? axl : axh;
        const unsigned short* const* ah = (sp == 2) ? ahl : ahh;
        const unsigned short* const* bb = (sp == 1) ? bl  : bh;
#pragma unroll 4
        for (int kt = 0; kt < 32; ++kt) {
            bf16x8 af[4], bf[4];
            if (kt < 16) {
#pragma unroll
                for (int i = 0; i < 4; ++i) af[i] = *(const bf16x8*)(ax[i] + kt * 32);
            } else {
#pragma unroll
                for (int i = 0; i < 4; ++i) af[i] = *(const bf16x8*)(ah[i] + (kt - 16) * 32);
            }
#pragma unroll
            for (int j = 0; j < 4; ++j) bf[j] = *(const bf16x8*)(bb[j] + kt * 32);
#pragma unroll
            for (int i = 0; i < 4; ++i)
#pragma unroll
                for (int j = 0; j < 4; ++j)
                    acc[i][j] = __builtin_amdgcn_mfma_f32_16x16x32_bf16(af[i], bf[j], acc[i][j], 0, 0, 0);
        }
    }
#pragma unroll
    for (int i = 0; i < 4; ++i)
#pragma unroll
        for (int j = 0; j < 4; ++j)
#pragma unroll
            for (int r = 0; r < 4; ++r)
                zt[wm * 64 + i * 16 + lg * 4 + r][wn * 64 + j * 16 + lr] = acc[i][j][r];
    __syncthreads();

    {
        int m_loc = t >> 1;
        int gb = m0 + m_loc;
        float* hptr = d ? hB : hF;
        float* cptr = d ? cB : cF;
        unsigned short* ohi = hsp_out + ((size_t)(((pp ^ 1) * 2 + d)) * 2 + 0) * HS;
        unsigned short* olo = hsp_out + ((size_t)(((pp ^ 1) * 2 + d)) * 2 + 1) * HS;
#pragma unroll
        for (int q = 0; q < 16; ++q) {
            int ui   = (t & 1) * 16 + q;
            int unit = u0 + ui;
            float zi = zt[m_loc][ui]      + bsum[ui];
            float zf = zt[m_loc][32 + ui] + bsum[32 + ui];
            float zg = zt[m_loc][64 + ui] + bsum[64 + ui];
            float zo = zt[m_loc][96 + ui] + bsum[96 + ui];
            float c  = cptr[(size_t)gb * 512 + unit];
            c = sigm(zf) * c + sigm(zi) * tanhf(zg);
            float hh = sigm(zo) * tanhf(c);
            cptr[(size_t)gb * 512 + unit] = c;
            hptr[(size_t)gb * 512 + unit] = hh;
            unsigned short hi = f2bf(hh);
            ohi[(size_t)gb * 512 + unit] = hi;
            olo[(size_t)gb * 512 + unit] = f2bf(hh - bf2f(hi));
        }
    }
}

// ---------------------------------------------------------------- tier-2: compose z-GEMM (fp32)
__global__ __launch_bounds__(256)
void k_compose_z(const float* __restrict__ e,
                 const float* __restrict__ hF, const float* __restrict__ hB,
                 const float* __restrict__ Wih_f, const float* __restrict__ Whh_f,
                 const float* __restrict__ bih_f, const float* __restrict__ bhh_f,
                 const float* __restrict__ Wih_b, const float* __restrict__ Whh_b,
                 const float* __restrict__ bih_b, const float* __restrict__ bhh_b,
                 float* __restrict__ zbuf, int stepk)
{
    __shared__ float As[16][64];
    __shared__ float Bs[16][64];
    const int d  = blockIdx.z;
    const int Mb = blockIdx.y * 64;
    const int Nb = blockIdx.x * 64;
    const int t  = threadIdx.x;

    const float* Wih = d ? Wih_b : Wih_f;
    const float* Whh = d ? Whh_b : Whh_f;
    const float* bih = d ? bih_b : bih_f;
    const float* bhh = d ? bhh_b : bhh_f;
    const float* h   = d ? hB : hF;
    const int child  = d ? (7 - stepk) : stepk;

    const int ml = t & 63;
    const int ko = (t >> 6) * 4;
    const int m  = Mb + ml;
    const int g  = m >> 4, b = m & 15;
    const float* xrow = e + ((size_t)((g * 8 + child) * 16 + b)) * S_;
    const float* hrow = h + (size_t)m * S_;
    const int n  = Nb + ml;
    const float* wi = Wih + (size_t)n * S_;
    const float* wh = Whh + (size_t)n * S_;

    const int tx = t & 15, ty = t >> 4;
    float acc[4][4] = {};

    for (int kk = 0; kk < 1024; kk += 16) {
        const float* ar = (kk < 512) ? (xrow + kk + ko) : (hrow + kk - 512 + ko);
        const float* br = (kk < 512) ? (wi + kk + ko)   : (wh + kk - 512 + ko);
        float4 av = *(const float4*)ar;
        float4 bv = *(const float4*)br;
        __syncthreads();
        As[ko + 0][ml] = av.x; As[ko + 1][ml] = av.y; As[ko + 2][ml] = av.z; As[ko + 3][ml] = av.w;
        Bs[ko + 0][ml] = bv.x; Bs[ko + 1][ml] = bv.y; Bs[ko + 2][ml] = bv.z; Bs[ko + 3][ml] = bv.w;
        __syncthreads();
#pragma unroll
        for (int k = 0; k < 16; ++k) {
            float a[4], bb[4];
#pragma unroll
            for (int i = 0; i < 4; ++i) a[i]  = As[k][ty * 4 + i];
#pragma unroll
            for (int j = 0; j < 4; ++j) bb[j] = Bs[k][tx * 4 + j];
#pragma unroll
            for (int i = 0; i < 4; ++i)
#pragma unroll
                for (int j = 0; j < 4; ++j) acc[i][j] += a[i] * bb[j];
        }
    }
#pragma unroll
    for (int i = 0; i < 4; ++i) {
        int mm = Mb + ty * 4 + i;
#pragma unroll
        for (int j = 0; j < 4; ++j) {
            int nn = Nb + tx * 4 + j;
            zbuf[((size_t)(d * 512 + mm)) * S4_ + nn] = acc[i][j] + bih[nn] + bhh[nn];
        }
    }
}

// ---------------------------------------------------------------- tier-2: compose gate update
__global__ __launch_bounds__(256)
void k_compose_gates(const float* __restrict__ zbuf,
                     float* __restrict__ hF, float* __restrict__ cF,
                     float* __restrict__ hB, float* __restrict__ cB)
{
    int idx = blockIdx.x * 256 + threadIdx.x;
    int d   = idx >> 18;
    int rem = idx & ((1 << 18) - 1);
    int gb  = rem >> 9;
    int u   = rem & 511;
    const float* z = zbuf + ((size_t)(d * 512 + gb)) * S4_;
    float zi = z[u], zf = z[u + 512], zg = z[u + 1024], zo = z[u + 1536];
    float* hptr = d ? hB : hF;
    float* cptr = d ? cB : cF;
    float c = cptr[gb * S_ + u];
    c = sigm(zf) * c + sigm(zi) * tanhf(zg);
    hptr[gb * S_ + u] = sigm(zo) * tanhf(c);
    cptr[gb * S_ + u] = c;
}

// ---------------------------------------------------------------- comp = tanh([hF|hB] @ Wc.T + bc)
// optional bf16 split outputs (v3 path passes pointers; tier-2 passes null)
__global__ __launch_bounds__(256)
void k_comp(const float* __restrict__ hF, const float* __restrict__ hB,
            const float* __restrict__ Wc, const float* __restrict__ bc,
            float* __restrict__ comp,
            unsigned short* __restrict__ comphi, unsigned short* __restrict__ complo)
{
    __shared__ float As[16][64];
    __shared__ float Bs[16][64];
    const int Mb = blockIdx.y * 64;
    const int Nb = blockIdx.x * 64;
    const int t  = threadIdx.x;
    const int ml = t & 63;
    const int ko = (t >> 6) * 4;
    const int m  = Mb + ml;
    const float* fr  = hF + (size_t)m * S_;
    const float* br_ = hB + (size_t)m * S_;
    const int n  = Nb + ml;
    const float* wr = Wc + (size_t)n * 1024;
    const int tx = t & 15, ty = t >> 4;
    float acc[4][4] = {};

    for (int kk = 0; kk < 1024; kk += 16) {
        const float* ar = (kk < 512) ? (fr + kk + ko) : (br_ + kk - 512 + ko);
        float4 av = *(const float4*)ar;
        float4 bv = *(const float4*)(wr + kk + ko);
        __syncthreads();
        As[ko + 0][ml] = av.x; As[ko + 1][ml] = av.y; As[ko + 2][ml] = av.z; As[ko + 3][ml] = av.w;
        Bs[ko + 0][ml] = bv.x; Bs[ko + 1][ml] = bv.y; Bs[ko + 2][ml] = bv.z; Bs[ko + 3][ml] = bv.w;
        __syncthreads();
#pragma unroll
        for (int k = 0; k < 16; ++k) {
            float a[4], bb[4];
#pragma unroll
            for (int i = 0; i < 4; ++i) a[i]  = As[k][ty * 4 + i];
#pragma unroll
            for (int j = 0; j < 4; ++j) bb[j] = Bs[k][tx * 4 + j];
#pragma unroll
            for (int i = 0; i < 4; ++i)
#pragma unroll
                for (int j = 0; j < 4; ++j) acc[i][j] += a[i] * bb[j];
        }
    }
#pragma unroll
    for (int i = 0; i < 4; ++i) {
        int mm = Mb + ty * 4 + i;
#pragma unroll
        for (int j = 0; j < 4; ++j) {
            int nn = Nb + tx * 4 + j;
            float v = tanhf(acc[i][j] + bc[nn]);
            comp[(size_t)mm * S_ + nn] = v;
            if (comphi) {
                unsigned short hi = f2bf(v);
                comphi[(size_t)mm * S_ + nn] = hi;
                complo[(size_t)mm * S_ + nn] = f2bf(v - bf2f(hi));
            }
        }
    }
}

// ---------------------------------------------------------------- MFMA zxt (bf16x3): M=5248(pad) N=2048 K=512
// Output layout identical to tier-2 k_zx: zxt[((s*64+blk)*4+g)*128 + b*8 + ui]
__global__ __launch_bounds__(256)
void k_zx2(const unsigned short* __restrict__ ehi, const unsigned short* __restrict__ elo,
           const unsigned short* __restrict__ comphi, const unsigned short* __restrict__ complo,
           const unsigned short* __restrict__ ophi, const unsigned short* __restrict__ oplo,
           const unsigned short* __restrict__ wshi, const unsigned short* __restrict__ wslo,
           const float* __restrict__ bih, const float* __restrict__ bhh,
           float* __restrict__ zxt)
{
    const int t  = threadIdx.x;
    const int w  = t >> 6, l = t & 63;
    const int wm = w & 1, wn = w >> 1;
    const int lr = l & 15, lg = l >> 4;
    const int Nb = blockIdx.x * 128;   // 16 n-tiles
    const int Mb = blockIdx.y * 128;   // 41 m-tiles

    const unsigned short *ah[4], *al[4];
#pragma unroll
    for (int i = 0; i < 4; ++i) {
        int m = Mb + wm * 64 + i * 16 + lr;
        int s = m >> 4; if (s > 320) s = 320;
        int b = m & 15;
        const unsigned short *ph, *pl;
        if (s == 0) { ph = ophi; pl = oplo; }
        else {
            int j = s - 1, g = j / 10, r = j - g * 10;
            if (r == 0)      { ph = ophi; pl = oplo; }
            else if (r <= 8) { size_t rr = ((size_t)((g * 8 + r - 1) * 16 + b)) * 512; ph = ehi + rr; pl = elo + rr; }
            else             { size_t rr = ((size_t)(g * 16 + b)) * 512; ph = comphi + rr; pl = complo + rr; }
        }
        ah[i] = ph + lg * 8; al[i] = pl + lg * 8;
    }
    const unsigned short *bh[4], *bl[4];
#pragma unroll
    for (int j = 0; j < 4; ++j) {
        size_t br = ((size_t)(Nb + wn * 64 + j * 16 + lr)) * 512 + lg * 8;
        bh[j] = wshi + br; bl[j] = wslo + br;
    }

    f32x4 acc[4][4] = {};
    for (int sp = 0; sp < 3; ++sp) {
        const unsigned short* const* aa = (sp == 2) ? al : ah;
        const unsigned short* const* bb = (sp == 1) ? bl : bh;
#pragma unroll 4
        for (int kt = 0; kt < 16; ++kt) {
            bf16x8 af[4], bf[4];
#pragma unroll
            for (int i = 0; i < 4; ++i) af[i] = *(const bf16x8*)(aa[i] + kt * 32);
#pragma unroll
            for (int j = 0; j < 4; ++j) bf[j] = *(const bf16x8*)(bb[j] + kt * 32);
#pragma unroll
            for (int i = 0; i < 4; ++i)
#pragma unroll
                for (int j = 0; j < 4; ++j)
                    acc[i][j] = __builtin_amdgcn_mfma_f32_16x16x32_bf16(af[i], bf[j], acc[i][j], 0, 0, 0);
        }
    }

    float bsumv[4];
#pragma unroll
    for (int j = 0; j < 4; ++j) {
        int n = Nb + wn * 64 + j * 16 + lr;
        bsumv[j] = bih[n] + bhh[n];
    }
#pragma unroll
    for (int i = 0; i < 4; ++i) {
#pragma unroll
        for (int r = 0; r < 4; ++r) {
            int m = Mb + wm * 64 + i * 16 + lg * 4 + r;
            if (m < MZX_) {
                int ss = m >> 4, bb2 = m & 15;
#pragma unroll
                for (int j = 0; j < 4; ++j) {
                    int n = Nb + wn * 64 + j * 16 + lr;
                    int g = n >> 9, un = n & 511;
                    zxt[(((size_t)ss * 64 + (un >> 3)) * 4 + g) * 128 + bb2 * 8 + (un & 7)]
                        = acc[i][j][r] + bsumv[j];
                }
            }
        }
    }
}

// ---------------------------------------------------------------- tier-2: fp32 zxt
__global__ __launch_bounds__(256)
void k_zx(const int* __restrict__ tokens, const float* __restrict__ emb,
          const float* __restrict__ e, const float* __restrict__ comp,
          const float* __restrict__ Wih, const float* __restrict__ bih,
          const float* __restrict__ bhh, float* __restrict__ zxt)
{
    __shared__ float As[16][64];
    __shared__ float Bs[16][64];
    const int Mb = blockIdx.y * 64;
    const int Nb = blockIdx.x * 64;
    const int t  = threadIdx.x;
    const int ml = t & 63;
    const int ko = (t >> 6) * 4;

    int m = Mb + ml;
    int s = m >> 4; if (s > 320) s = 320;
    int b = m & 15;
    const float* xrow;
    if (s == 0) xrow = emb + (size_t)tokens[0] * S_;
    else {
        int j = s - 1, g = j / 10, r = j - g * 10;
        if (r == 0)      xrow = emb + (size_t)tokens[0] * S_;
        else if (r <= 8) xrow = e + ((size_t)((g * 8 + r - 1) * 16 + b)) * S_;
        else             xrow = comp + ((size_t)(g * 16 + b)) * S_;
    }
    const int n = Nb + ml;
    const float* wr = Wih + (size_t)n * S_;
    const int tx = t & 15, ty = t >> 4;
    float acc[4][4] = {};

    for (int kk = 0; kk < 512; kk += 16) {
        float4 av = *(const float4*)(xrow + kk + ko);
        float4 bv = *(const float4*)(wr + kk + ko);
        __syncthreads();
        As[ko + 0][ml] = av.x; As[ko + 1][ml] = av.y; As[ko + 2][ml] = av.z; As[ko + 3][ml] = av.w;
        Bs[ko + 0][ml] = bv.x; Bs[ko + 1][ml] = bv.y; Bs[ko + 2][ml] = bv.z; Bs[ko + 3][ml] = bv.w;
        __syncthreads();
#pragma unroll
        for (int k = 0; k < 16; ++k) {
            float a[4], bb[4];
#pragma unroll
            for (int i = 0; i < 4; ++i) a[i]  = As[k][ty * 4 + i];
#pragma unroll
            for (int j = 0; j < 4; ++j) bb[j] = Bs[k][tx * 4 + j];
#pragma unroll
            for (int i = 0; i < 4; ++i)
#pragma unroll
                for (int j = 0; j < 4; ++j) acc[i][j] += a[i] * bb[j];
        }
    }
#pragma unroll
    for (int i = 0; i < 4; ++i) {
        int mm = Mb + ty * 4 + i;
        int ss = mm >> 4, bb2 = mm & 15;
#pragma unroll
        for (int j = 0; j < 4; ++j) {
            int nn = Nb + tx * 4 + j;
            int g = nn >> 9, un = nn & 511;
            zxt[(((size_t)ss * 64 + (un >> 3)) * 4 + g) * 128 + bb2 * 8 + (un & 7)]
                = acc[i][j] + bih[nn] + bhh[nn];
        }
    }
}

// ---------------------------------------------------------------- persistent stack-LSTM scan (r5 structure)
__global__ __launch_bounds__(256)
void k_scan(const float* __restrict__ zxt, const float* __restrict__ Whh,
            float* __restrict__ hseq, float* __restrict__ hp, int* __restrict__ cnt)
{
    __shared__ float4 wlin[8 * 513];
    __shared__ float4 hlin[8 * 257];
    __shared__ float  zred[8][32 * 17];
    const int t  = threadIdx.x;
    const int u0 = (int)blockIdx.x * 8;

#pragma unroll 4
    for (int q = 0; q < 16; ++q) {
        int v  = t * 16 + q;
        int kc = v >> 9, r = v & 511;
        int k4 = r >> 5, rr = r & 31;
        int j  = rr >> 3, nq = rr & 7;
        int lrr = nq * 4 + j;
        int n  = (lrr >> 3) * 512 + u0 + (lrr & 7);
        int k  = kc * 64 + k4 * 4;
        wlin[kc * 513 + r] = *(const float4*)(Whh + (size_t)n * S_ + k);
    }

    const int kc = t >> 5;
    const int pt = t & 31;
    const int bq = pt >> 3;
    const int nq = pt & 7;
    const int hbase = kc * 257 + bq;
    const int wbase = kc * 513 + nq;

    const int gb_b  = t >> 3;
    const int gb_ui = t & 7;
    float creg = 0.0f;

    for (int s = 0; s < NSTEPS_; ++s) {
        float zxr[4];
        if (t < 128) {
            const float* zp = zxt + (((size_t)s * 64 + blockIdx.x) * 4) * 128 + t;
#pragma unroll
            for (int g = 0; g < 4; ++g) zxr[g] = zp[g * 128];
        }
        if (s > 0) {
            if (t == 0) {
                while (__hip_atomic_load(&cnt[s - 1], __ATOMIC_RELAXED,
                                         __HIP_MEMORY_SCOPE_AGENT) < SCAN_NB) { }
            }
            __syncthreads();
        }
        {
            int b = t >> 4;
            int kbase = (t & 15) * 32;
            const float4* src = (const float4*)(hseq + (size_t)s * 8192 + b * S_ + kbase);
#pragma unroll
            for (int q = 0; q < 8; ++q) {
                int k = kbase + q * 4;
                hlin[(k >> 6) * 257 + ((k & 63) >> 2) * 16 + (b >> 2) + (b & 3) * 4] = src[q];
            }
        }
        __syncthreads();
        float acc[4][4] = {{0.f,0.f,0.f,0.f},{0.f,0.f,0.f,0.f},{0.f,0.f,0.f,0.f},{0.f,0.f,0.f,0.f}};
#pragma unroll
        for (int k4 = 0; k4 < 16; ++k4) {
            float4 hv[4], wv[4];
#pragma unroll
            for (int i = 0; i < 4; ++i) hv[i] = hlin[hbase + k4 * 16 + i * 4];
#pragma unroll
            for (int j = 0; j < 4; ++j) wv[j] = wlin[wbase + k4 * 32 + j * 8];
#pragma unroll
            for (int i = 0; i < 4; ++i)
#pragma unroll
                for (int j = 0; j < 4; ++j)
                    acc[i][j] += hv[i].x * wv[j].x + hv[i].y * wv[j].y
                               + hv[i].z * wv[j].z + hv[i].w * wv[j].w;
        }
#pragma unroll
        for (int i = 0; i < 4; ++i)
#pragma unroll
            for (int j = 0; j < 4; ++j)
                zred[kc][pt * 17 + i * 4 + j] = acc[i][j];
        __syncthreads();
        if (t < 128) {
            float z[4];
#pragma unroll
            for (int g = 0; g < 4; ++g) {
                int lrr = g * 8 + gb_ui;
                int idx = ((gb_b >> 2) * 8 + (lrr >> 2)) * 17 + (gb_b & 3) * 4 + (lrr & 3);
                float sum = zred[0][idx];
#pragma unroll
                for (int c = 1; c < 8; ++c) sum += zred[c][idx];
                z[g] = zxr[g] + sum;
            }
            creg = sigm(z[1]) * creg + sigm(z[0]) * tanhf(z[2]);
            float hh = sigm(z[3]) * tanhf(creg);
            __hip_atomic_store(&hseq[(size_t)(s + 1) * 8192 + gb_b * S_ + u0 + gb_ui], hh,
                               __ATOMIC_RELAXED, __HIP_MEMORY_SCOPE_AGENT);
            if (s >= 1) {
                int j2 = s - 1, g2 = j2 / 10, r = j2 - g2 * 10;
                if (r <= 7)
                    hp[((size_t)((g2 * 8 + r) * 16 + gb_b)) * S_ + u0 + gb_ui] = hh;
            }
        }
        asm volatile("s_waitcnt vmcnt(0)" ::: "memory");
        __syncthreads();
        if (t == 0)
            __hip_atomic_fetch_add(&cnt[s], 1, __ATOMIC_RELAXED,
                                   __HIP_MEMORY_SCOPE_AGENT);
    }
}

// ---------------------------------------------------------------- token logit (exact fp32)
__global__ __launch_bounds__(64)
void k_tok(const int* __restrict__ tokens, const float* __restrict__ hp,
           const float* __restrict__ Wout, const float* __restrict__ bout,
           float* __restrict__ tl)
{
    int row  = blockIdx.x;
    int lane = threadIdx.x;
    int tok  = tokens[row];
    const float4* a = (const float4*)(hp + (size_t)row * S_);
    const float4* w = (const float4*)(Wout + (size_t)tok * S_);
    float s = 0.f;
    for (int q = lane; q < 128; q += 64) {
        float4 av = a[q], wv = w[q];
        s += av.x * wv.x + av.y * wv.y + av.z * wv.z + av.w * wv.w;
    }
    for (int off = 32; off; off >>= 1) s += __shfl_down(s, off);
    if (lane == 0) tl[row] = s + bout[tok];
}

// ---------------------------------------------------------------- fp32 -> bf16 conversion
__global__ __launch_bounds__(256)
void k_cvt(const float* __restrict__ src, unsigned short* __restrict__ dst, int n)
{
    int i = (blockIdx.x * 256 + threadIdx.x) * 8;
    if (i >= n) return;
    float4 a = *(const float4*)(src + i);
    float4 b = *(const float4*)(src + i + 4);
    union { unsigned short u[8]; uint4 v; } r;
    r.u[0] = f2bf(a.x); r.u[1] = f2bf(a.y); r.u[2] = f2bf(a.z); r.u[3] = f2bf(a.w);
    r.u[4] = f2bf(b.x); r.u[5] = f2bf(b.y); r.u[6] = f2bf(b.z); r.u[7] = f2bf(b.w);
    *(uint4*)(dst + i) = r.v;
}

// ---------------------------------------------------------------- MFMA logits GEMM + online LSE partials
__global__ __launch_bounds__(256)
void k_lse_mfma(const unsigned short* __restrict__ hpb,
                const unsigned short* __restrict__ woutb,
                const float* __restrict__ bout, float* __restrict__ pmax,
                float* __restrict__ psum)
{
    __shared__ float maxsh[128][2];
    __shared__ float sumsh[128][2];
    __shared__ float mrow_sh[128];
    const int t  = threadIdx.x;
    const int w  = t >> 6, l = t & 63;
    const int wm = w & 1, wn = w >> 1;
    const int lr = l & 15, lg = l >> 4;
    const int Mb = blockIdx.x * 128;
    const int Nb = blockIdx.y * 128;

    f32x4 acc[4][4] = {};
    const unsigned short* arow[4];
    const unsigned short* brow[4];
#pragma unroll
    for (int i = 0; i < 4; ++i)
        arow[i] = hpb + (size_t)(Mb + wm * 64 + i * 16 + lr) * 512 + lg * 8;
#pragma unroll
    for (int j = 0; j < 4; ++j)
        brow[j] = woutb + (size_t)(Nb + wn * 64 + j * 16 + lr) * 512 + lg * 8;

    for (int kt = 0; kt < 16; ++kt) {
        bf16x8 af[4], bf[4];
#pragma unroll
        for (int i = 0; i < 4; ++i) af[i] = *(const bf16x8*)(arow[i] + kt * 32);
#pragma unroll
        for (int j = 0; j < 4; ++j) bf[j] = *(const bf16x8*)(brow[j] + kt * 32);
#pragma unroll
        for (int i = 0; i < 4; ++i)
#pragma unroll
            for (int j = 0; j < 4; ++j)
                acc[i][j] = __builtin_amdgcn_mfma_f32_16x16x32_bf16(af[i], bf[j], acc[i][j], 0, 0, 0);
    }

    float bv[4];
#pragma unroll
    for (int j = 0; j < 4; ++j) bv[j] = bout[Nb + wn * 64 + j * 16 + lr];

    float rmax[4][4];
#pragma unroll
    for (int mi = 0; mi < 4; ++mi)
#pragma unroll
        for (int r = 0; r < 4; ++r) {
            float m = -INFINITY;
#pragma unroll
            for (int j = 0; j < 4; ++j) m = fmaxf(m, acc[mi][j][r] + bv[j]);
            m = fmaxf(m, __shfl_xor(m, 1));
            m = fmaxf(m, __shfl_xor(m, 2));
            m = fmaxf(m, __shfl_xor(m, 4));
            m = fmaxf(m, __shfl_xor(m, 8));
            rmax[mi][r] = m;
        }
    if (lr == 0) {
#pragma unroll
        for (int mi = 0; mi < 4; ++mi)
#pragma unroll
            for (int r = 0; r < 4; ++r)
                maxsh[wm * 64 + mi * 16 + lg * 4 + r][wn] = rmax[mi][r];
    }
    __syncthreads();
    if (t < 128) mrow_sh[t] = fmaxf(maxsh[t][0], maxsh[t][1]);
    __syncthreads();
#pragma unroll
    for (int mi = 0; mi < 4; ++mi)
#pragma unroll
        for (int r = 0; r < 4; ++r) {
            float M = mrow_sh[wm * 64 + mi * 16 + lg * 4 + r];
            float s = 0.f;
#pragma unroll
            for (int j = 0; j < 4; ++j) s += expf(acc[mi][j][r] + bv[j] - M);
            s += __shfl_xor(s, 1);
            s += __shfl_xor(s, 2);
            s += __shfl_xor(s, 4);
            s += __shfl_xor(s, 8);
            if (lr == 0) sumsh[wm * 64 + mi * 16 + lg * 4 + r][wn] = s;
        }
    __syncthreads();
    if (t < 128) {
        size_t off = (size_t)(Mb + t) * NT_LSE_ + blockIdx.y;
        pmax[off] = mrow_sh[t];
        psum[off] = sumsh[t][0] + sumsh[t][1];
    }
}

// ---------------------------------------------------------------- final reduce
__global__ __launch_bounds__(256)
void k_final(const float* __restrict__ pmax, const float* __restrict__ psum,
             const float* __restrict__ tl, float* __restrict__ loss)
{
    int r = blockIdx.x * 256 + threadIdx.x;
    const float* pm = pmax + (size_t)r * NT_LSE_;
    const float* ps = psum + (size_t)r * NT_LSE_;
    float M = -INFINITY, Ssum = 0.f;
    for (int nt = 0; nt < NT_LSE_; ++nt) {
        float m2 = pm[nt], s2 = ps[nt];
        float nm = fmaxf(M, m2);
        Ssum = Ssum * expf(M - nm) + s2 * expf(m2 - nm);
        M = nm;
    }
    loss[r] = M + logf(Ssum) - tl[r];
}

// ================================================================ host launcher
extern "C" void kernel_launch(void* const* d_in, const int* in_sizes, int n_in,
                              void* d_out, int out_size, void* d_ws, size_t ws_size,
                              hipStream_t stream)
{
    const int*   tokens = (const int*)d_in[0];
    const float* emb    = (const float*)d_in[1];
    const float* Wih_s  = (const float*)d_in[2];
    const float* Whh_s  = (const float*)d_in[3];
    const float* bih_s  = (const float*)d_in[4];
    const float* bhh_s  = (const float*)d_in[5];
    const float* Wih_f  = (const float*)d_in[6];
    const float* Whh_f  = (const float*)d_in[7];
    const float* bih_f  = (const float*)d_in[8];
    const float* bhh_f  = (const float*)d_in[9];
    const float* Wih_b  = (const float*)d_in[10];
    const float* Whh_b  = (const float*)d_in[11];
    const float* bih_b  = (const float*)d_in[12];
    const float* bhh_b  = (const float*)d_in[13];
    const float* Wc     = (const float*)d_in[14];
    const float* bc     = (const float*)d_in[15];
    const float* Wout   = (const float*)d_in[16];
    const float* bout   = (const float*)d_in[17];
    float* loss = (float*)d_out;

    // ---------------- v3 layout (byte-based)
    char* base = (char*)d_ws;
    size_t o = 0;
    auto alloc = [&](size_t bytes) { char* p = base + o; o = (o + bytes + 255) & ~(size_t)255; return p; };

    unsigned short* ehi  = (unsigned short*)alloc((size_t)T_ * B_ * S_ * 2);
    unsigned short* elo  = (unsigned short*)alloc((size_t)T_ * B_ * S_ * 2);
    float* hF  = (float*)alloc((size_t)GB_ * S_ * 4);
    float* hB  = (float*)alloc((size_t)GB_ * S_ * 4);
    float* cF  = (float*)alloc((size_t)GB_ * S_ * 4);       // zero region A start
    float* cB  = (float*)alloc((size_t)GB_ * S_ * 4);
    unsigned short* hsp = (unsigned short*)alloc((size_t)2 * 2 * 2 * GB_ * S_ * 2);  // [pp][d][hi/lo]; pp=0 zeroed
    int*   cnt  = (int*)alloc(512 * 4);                     // zero region B start
    float* hseq = (float*)alloc((size_t)(NSTEPS_ + 1) * B_ * S_ * 4);  // hseq[0] zeroed (own region!)
    float* comp = (float*)alloc((size_t)GB_ * S_ * 4);
    unsigned short* comphi = (unsigned short*)alloc((size_t)GB_ * S_ * 2);
    unsigned short* complo = (unsigned short*)alloc((size_t)GB_ * S_ * 2);
    unsigned short* ophi = (unsigned short*)alloc(S_ * 2);
    unsigned short* oplo = (unsigned short*)alloc(S_ * 2);
    unsigned short* wchi = (unsigned short*)alloc((size_t)2 * S4_ * 1024 * 2);
    unsigned short* wclo = (unsigned short*)alloc((size_t)2 * S4_ * 1024 * 2);
    unsigned short* wshi = (unsigned short*)alloc((size_t)S4_ * S_ * 2);
    unsigned short* wslo = (unsigned short*)alloc((size_t)S4_ * S_ * 2);
    float* hp   = (float*)alloc((size_t)T_ * B_ * S_ * 4);
    float* pmax = (float*)alloc((size_t)T_ * B_ * NT_LSE_ * 4);
    float* psum = (float*)alloc((size_t)T_ * B_ * NT_LSE_ * 4);
    float* tl   = (float*)alloc((size_t)T_ * B_ * 4);
    float* zxt  = (float*)alloc((size_t)MZX_ * S4_ * 4);
    size_t need_v3 = o;

    // overlays (cross-dispatch only — safe via kernel-boundary fences):
    unsigned short* hpb   = wshi;            // 4MB over wshi+wslo (dead after k_zx2)
    unsigned short* woutb = (unsigned short*)zxt;  // 32MB over zxt (dead after k_scan)

    if (ws_size >= need_v3) {
        // zero: cF+cB+hsp[pp=0] (contiguous), cnt+hseq[0] (contiguous)
        hipMemsetAsync(cF, 0, (size_t)2 * GB_ * S_ * 4 + (size_t)4 * GB_ * S_ * 2, stream);
        hipMemsetAsync(cnt, 0, 512 * 4 + (size_t)B_ * S_ * 4 + 256, stream);

        k_gather2<<<T_ * B_, 128, 0, stream>>>(tokens, emb, ehi, elo);
        k_osplit<<<1, 128, 0, stream>>>(tokens, emb, ophi, oplo);
        k_wsplit_cat<<<2048, 256, 0, stream>>>(Wih_f, Whh_f, Wih_b, Whh_b, wchi, wclo);
        k_wsplit_s<<<512, 256, 0, stream>>>(Wih_s, wshi, wslo);

        for (int k = 0; k < 8; ++k) {
            k_compose2<<<dim3(16, 4, 2), 256, 0, stream>>>(
                ehi, elo, wchi, wclo, hsp, hsp,
                bih_f, bhh_f, bih_b, bhh_b, hF, cF, hB, cB, k);
        }
        k_comp<<<dim3(8, 8), 256, 0, stream>>>(hF, hB, Wc, bc, comp, comphi, complo);
        k_zx2<<<dim3(16, 41), 256, 0, stream>>>(ehi, elo, comphi, complo, ophi, oplo,
                                                wshi, wslo, bih_s, bhh_s, zxt);
        k_scan<<<SCAN_NB, 256, 0, stream>>>(zxt, Whh_s, hseq, hp, cnt);

        k_cvt<<<(T_ * B_ * S_) / (256 * 8), 256, 0, stream>>>(hp, hpb, T_ * B_ * S_);
        k_cvt<<<(V_ * S_) / (256 * 8), 256, 0, stream>>>(Wout, woutb, V_ * S_);

        k_tok<<<T_ * B_, 64, 0, stream>>>(tokens, hp, Wout, bout, tl);
        k_lse_mfma<<<dim3(32, NT_LSE_), 256, 0, stream>>>(hpb, woutb, bout, pmax, psum);
        k_final<<<16, 256, 0, stream>>>(pmax, psum, tl, loss);
    } else {
        // ---------------- tier-2: proven round-6 path (fp32 compose/zx + MFMA LSE)
        float* ws = (float*)d_ws;
        size_t off = 0;
        float* e2    = ws + off; off += (size_t)T_ * B_ * S_;
        float* hF2   = ws + off; off += (size_t)GB_ * S_;
        float* cF2   = ws + off; off += (size_t)GB_ * S_;
        float* hB2   = ws + off; off += (size_t)GB_ * S_;
        float* cB2   = ws + off; off += (size_t)GB_ * S_;
        int*   cnt2  = (int*)(ws + off); off += 512;
        float* hseq2 = ws + off; off += (size_t)(NSTEPS_ + 1) * B_ * S_;
        size_t zero_end = (size_t)T_ * B_ * S_ + 4 * (size_t)GB_ * S_ + 512 + (size_t)B_ * S_;
        float* zbuf2 = ws + off; off += (size_t)2 * GB_ * S4_;
        float* comp2 = ws + off; off += (size_t)GB_ * S_;
        float* hp2   = ws + off; off += (size_t)T_ * B_ * S_;
        float* pmax2 = ws + off; off += (size_t)T_ * B_ * NT_LSE_;
        float* psum2 = ws + off; off += (size_t)T_ * B_ * NT_LSE_;
        float* tl2   = ws + off; off += (size_t)T_ * B_;
        float* zxt2  = ws + off; off += (size_t)MZX_ * S4_;

        unsigned short* hpb2   = (unsigned short*)zbuf2;
        unsigned short* woutb2 = (unsigned short*)zxt2;

        size_t zs = (size_t)T_ * B_ * S_;
        hipMemsetAsync(hF2, 0, (zero_end - zs) * sizeof(float), stream);

        k_gather<<<T_ * B_, 128, 0, stream>>>(tokens, emb, e2);
        for (int k = 0; k < 8; ++k) {
            k_compose_z<<<dim3(32, 8, 2), 256, 0, stream>>>(
                e2, hF2, hB2, Wih_f, Whh_f, bih_f, bhh_f,
                Wih_b, Whh_b, bih_b, bhh_b, zbuf2, k);
            k_compose_gates<<<2048, 256, 0, stream>>>(zbuf2, hF2, cF2, hB2, cB2);
        }
        k_comp<<<dim3(8, 8), 256, 0, stream>>>(hF2, hB2, Wc, bc, comp2,
                                               (unsigned short*)nullptr, (unsigned short*)nullptr);
        k_zx<<<dim3(32, 81), 256, 0, stream>>>(tokens, emb, e2, comp2,
                                               Wih_s, bih_s, bhh_s, zxt2);
        k_scan<<<SCAN_NB, 256, 0, stream>>>(zxt2, Whh_s, hseq2, hp2, cnt2);

        k_cvt<<<(T_ * B_ * S_) / (256 * 8), 256, 0, stream>>>(hp2, hpb2, T_ * B_ * S_);
        k_cvt<<<(V_ * S_) / (256 * 8), 256, 0, stream>>>(Wout, woutb2, V_ * S_);

        k_tok<<<T_ * B_, 64, 0, stream>>>(tokens, hp2, Wout, bout, tl2);
        k_lse_mfma<<<dim3(32, NT_LSE_), 256, 0, stream>>>(hpb2, woutb2, bout, pmax2, psum2);
        k_final<<<16, 256, 0, stream>>>(pmax2, psum2, tl2, loss);
    }
}